// Round 1
// 724.987 us; speedup vs baseline: 1.1926x; 1.1926x over previous
//
#include <hip/hip_runtime.h>
#include <hip/hip_bf16.h>

// Problem constants (from reference)
#define S_DIM 8192
#define H_DIM 7168
#define D0_DIM 1536
#define D1_DIM 576
#define N_DIM 2112          // D0 + D1
#define R_DIM 64
#define LA_WIDTH 128        // 2 * R

// Extended-K fused layout: K' = H + 128 (64 lora cols per slice, complementary
// halves zeroed in Wext so one GEMM computes base + LoRA-B contribution).
#define K_EXT 7296
#define NT32 228            // K_EXT / 32 k-blocks
#define N_PAD 2176          // 17 * 128
#define KSPLIT 8
#define KCHUNK 896          // H_DIM / KSPLIT

// Tiled-swizzled staging layout for xe/we:
//   [rblock = row/16][kblock = k/32][64 slots][8 shorts]  (1 KB per block)
//   slot = (row%16)*4 + cphys,  cphys = ((k%32)/8) ^ (row&3)
// The XOR swizzle makes the MFMA fragment ds_read_b128 pattern exactly
// 2 lanes/bank (free, m136), while each global_load_lds reads 1 KB
// contiguous into a LINEAR LDS dest (rule 21: swizzle baked into source).
#define XE_RB 512           // S_DIM / 16
#define WE_RB 136           // N_PAD / 16

typedef __attribute__((ext_vector_type(4))) float f32x4;
typedef __attribute__((ext_vector_type(8))) short bf16x8;
typedef __attribute__((ext_vector_type(4))) short bf16x4;

__device__ __forceinline__ short f2bf(float f) {
    union { __hip_bfloat16 h; short s; } u;
    u.h = __float2bfloat16(f);
    return u.s;
}

__device__ __forceinline__ bf16x8 pack8(f32x4 a, f32x4 b) {
    bf16x8 r;
    r[0] = f2bf(a[0]); r[1] = f2bf(a[1]); r[2] = f2bf(a[2]); r[3] = f2bf(a[3]);
    r[4] = f2bf(b[0]); r[5] = f2bf(b[1]); r[6] = f2bf(b[2]); r[7] = f2bf(b[3]);
    return r;
}

__device__ __forceinline__ void gload_lds16(const short* g, short* l) {
    __builtin_amdgcn_global_load_lds(
        (const __attribute__((address_space(1))) unsigned int*)(const void*)g,
        (__attribute__((address_space(3))) unsigned int*)(void*)l, 16, 0, 0);
}

// ---------------------------------------------------------------------------
// convert_w: W fp32 [N,H] -> we tiled-swizzled bf16, kblocks 0..223
// ---------------------------------------------------------------------------
__global__ __launch_bounds__(256)
void convert_w(const float* __restrict__ W, short* __restrict__ we) {
    unsigned id = blockIdx.x * 256u + threadIdx.x;   // < 132*224*64
    unsigned rb  = id / 14336u;          // 224*64
    unsigned rem = id % 14336u;
    unsigned kb  = rem >> 6, sl = rem & 63u;
    unsigned r16 = sl >> 2;
    unsigned c   = (sl & 3u) ^ (r16 & 3u);
    unsigned row = rb * 16u + r16;
    unsigned k   = kb * 32u + c * 8u;
    const float* p = W + (size_t)row * H_DIM + k;
    f32x4 a = *(const f32x4*)p;
    f32x4 b = *(const f32x4*)(p + 4);
    *(bf16x8*)(we + ((size_t)rb * NT32 + kb) * 512u + sl * 8u) = pack8(a, b);
}

// convert_w_lora: fill we kblocks 224..227 (LoRA-B cols), all 136 rblocks:
//   row <  D0: [B0 row (64), zeros(64)] ; D0<=row<N: [zeros, B1 row-D0 (64)]
//   row >= N_DIM (pad): zeros
__global__ __launch_bounds__(256)
void convert_w_lora(const float* __restrict__ Bbuf, short* __restrict__ we) {
    unsigned id = blockIdx.x * 256u + threadIdx.x;   // < 136*4*64
    unsigned rb  = id >> 8;
    unsigned rem = id & 255u;
    unsigned kb4 = rem >> 6, sl = rem & 63u;
    unsigned r16 = sl >> 2;
    unsigned c   = (sl & 3u) ^ (r16 & 3u);
    unsigned row = rb * 16u + r16;
    unsigned k   = kb4 * 32u + c * 8u;               // 0..127 within lora cols
    bf16x8 v = {};
    if (row < N_DIM) {
        const bool s1 = row >= D0_DIM;
        const unsigned lo = s1 ? 64u : 0u;
        if (k >= lo && k < lo + 64u) {
            const float* p = Bbuf + ((size_t)(s1 ? 1u : 0u) * D0_DIM +
                                     (row - (s1 ? D0_DIM : 0u))) * R_DIM + (k - lo);
            f32x4 a = *(const f32x4*)p;
            f32x4 b = *(const f32x4*)(p + 4);
            v = pack8(a, b);
        }
    }
    *(bf16x8*)(we + ((size_t)rb * NT32 + (224u + kb4)) * 512u + sl * 8u) = v;
}

// ---------------------------------------------------------------------------
// lora_a_pass: K-split LoRA-A GEMM with convert_x fused into staging.
// Writes converted x to xe in the tiled-swizzled layout + fp32 partials.
// ---------------------------------------------------------------------------
__global__ __launch_bounds__(256, 2)
void lora_a_pass(const float* __restrict__ x, const float* __restrict__ A,
                 float* __restrict__ part, short* __restrict__ xe) {
    __shared__ __align__(16) short sX[128 * 40];
    __shared__ __align__(16) short sA[128 * 40];

    const int tid = threadIdx.x;
    const int m0 = blockIdx.x * 128;
    const int k0 = blockIdx.y * KCHUNK;
    const int wave = tid >> 6, lane = tid & 63;
    const int wm = (wave & 1) * 64, wn = (wave >> 1) * 64;
    const int fr = lane & 15, fq = lane >> 4;

    f32x4 acc[4][4] = {};

    const int srow = tid >> 1, shalf = (tid & 1) * 16;
    const float* xP = x + (size_t)(m0 + srow) * H_DIM + k0 + shalf;
    const float* aP = A + (size_t)srow * H_DIM + k0 + shalf;

    // tiled-swizzled xe destination
    const unsigned rbx = (unsigned)(m0 + srow) >> 4;
    const unsigned r16 = (unsigned)srow & 15u;
    const unsigned kb0 = (unsigned)k0 >> 5;          // blockIdx.y * 28
    const unsigned c0  = (unsigned)shalf >> 3;       // 0 or 2
    const unsigned sl0 = r16 * 4u + (c0 ^ (r16 & 3u));
    const unsigned sl1 = r16 * 4u + ((c0 + 1u) ^ (r16 & 3u));
    short* xeB = xe + ((size_t)rbx * NT32 + kb0) * 512u;

    short* sXw = sX + srow * 40 + shalf;
    short* sAw = sA + srow * 40 + shalf;
    const short* sXr = sX + (wm + fr) * 40 + fq * 8;
    const short* sAr = sA + (wn + fr) * 40 + fq * 8;

    for (int it = 0; it < KCHUNK / 32; ++it) {
        const float* px = xP + it * 32;
        const float* pa = aP + it * 32;
        f32x4 x0 = *(const f32x4*)(px);
        f32x4 x1 = *(const f32x4*)(px + 4);
        f32x4 x2 = *(const f32x4*)(px + 8);
        f32x4 x3 = *(const f32x4*)(px + 12);
        f32x4 a0 = *(const f32x4*)(pa);
        f32x4 a1 = *(const f32x4*)(pa + 4);
        f32x4 a2 = *(const f32x4*)(pa + 8);
        f32x4 a3 = *(const f32x4*)(pa + 12);
        bf16x8 px0 = pack8(x0, x1), px1 = pack8(x2, x3);
        bf16x8 pa0 = pack8(a0, a1), pa1 = pack8(a2, a3);

        // fused convert_x: tiled-swizzled store
        *(bf16x8*)(xeB + (size_t)it * 512 + sl0 * 8u) = px0;
        *(bf16x8*)(xeB + (size_t)it * 512 + sl1 * 8u) = px1;

        __syncthreads();
        *(bf16x8*)(sXw) = px0; *(bf16x8*)(sXw + 8) = px1;
        *(bf16x8*)(sAw) = pa0; *(bf16x8*)(sAw + 8) = pa1;
        __syncthreads();

        bf16x8 af[4], bfg[4];
#pragma unroll
        for (int i = 0; i < 4; ++i) af[i] = *(const bf16x8*)(sXr + i * 16 * 40);
#pragma unroll
        for (int i = 0; i < 4; ++i) bfg[i] = *(const bf16x8*)(sAr + i * 16 * 40);
#pragma unroll
        for (int mi = 0; mi < 4; ++mi)
#pragma unroll
            for (int ni = 0; ni < 4; ++ni)
                acc[mi][ni] = __builtin_amdgcn_mfma_f32_16x16x32_bf16(
                    af[mi], bfg[ni], acc[mi][ni], 0, 0, 0);
    }

    float* pBase = part + (size_t)blockIdx.y * S_DIM * LA_WIDTH;
#pragma unroll
    for (int ni = 0; ni < 4; ++ni) {
        const int col = wn + ni * 16 + fr;
#pragma unroll
        for (int mi = 0; mi < 4; ++mi) {
            const int row = m0 + wm + mi * 16 + fq * 4;
#pragma unroll
            for (int r = 0; r < 4; ++r)
                pBase[(size_t)(row + r) * LA_WIDTH + col] = acc[mi][ni][r];
        }
    }
}

// lora_reduce: la = sum of 8 partials -> bf16 -> xe kblocks 224..227
__global__ __launch_bounds__(256)
void lora_reduce(const float* __restrict__ part, short* __restrict__ xe) {
    unsigned id = blockIdx.x * 256u + threadIdx.x;   // < 8192*16
    unsigned row = id >> 4, c8 = (id & 15u) * 8u;
    f32x4 s0 = {}, s1 = {};
#pragma unroll
    for (int kz = 0; kz < KSPLIT; ++kz) {
        const float* p = part + ((size_t)kz * S_DIM + row) * LA_WIDTH + c8;
        s0 += *(const f32x4*)(p);
        s1 += *(const f32x4*)(p + 4);
    }
    unsigned rbx = row >> 4, r16 = row & 15u;
    unsigned kb = 224u + (c8 >> 5);
    unsigned cc = (c8 >> 3) & 3u;
    unsigned sl = r16 * 4u + (cc ^ (r16 & 3u));
    *(bf16x8*)(xe + ((size_t)rbx * NT32 + kb) * 512u + sl * 8u) = pack8(s0, s1);
}

// ---------------------------------------------------------------------------
// main_gemm_tiled: out = xext @ Wext^T + bias  (K = 7296 includes LoRA-B)
// BM=256 x BN=128, BK=32, ring-3 LDS (72 KB -> 2 blocks/CU), 4 waves each
// owning a 128x64 sub-tile. Counted vmcnt(6) pipeline (never drains to 0 in
// the main loop), raw s_barrier (no vmcnt(0) drain), setprio around the MFMA
// cluster, conflict-free swizzled ds_read (2 lanes/bank).
// 544 blocks (32 m x 17 n, n-fast for xe-panel sharing) -> ~2.1 rounds of the
// 512 concurrently-resident blocks: good tail packing.
// ---------------------------------------------------------------------------
__global__ __launch_bounds__(256, 2)
void main_gemm_tiled(const short* __restrict__ xe, const short* __restrict__ we,
                     const float* __restrict__ bias, float* __restrict__ out) {
    __shared__ __align__(16) short lds[3 * 12288];   // 3 bufs x (A 16KB | B 8KB)

    const int tid = threadIdx.x;
    const int bx = blockIdx.x;                 // 0..543
    const int m0 = (bx / 17) * 256;
    const int n0 = (bx % 17) * 128;

    const int wave = tid >> 6, lane = tid & 63;
    const int wm = (wave & 1) * 128;
    const int wn = (wave >> 1) * 64;
    const int fr = lane & 15, fq = lane >> 4;

    f32x4 acc[8][4] = {};

    // per-tile staging: 24 x 1KB blocks (A rblocks 0..15, B rblocks 0..7);
    // wave w issues 6 contiguous-source global_load_lds.
    const short* gp[6];
    int ldoff[6];
    {
        const short* xe_pan = xe + (size_t)(m0 >> 4) * NT32 * 512 + lane * 8;
        const short* we_pan = we + (size_t)(n0 >> 4) * NT32 * 512 + lane * 8;
#pragma unroll
        for (int i = 0; i < 6; ++i) {
            const int idx = wave * 6 + i;
            if (idx < 16) { gp[i] = xe_pan + (size_t)idx * NT32 * 512; ldoff[i] = idx * 512; }
            else          { gp[i] = we_pan + (size_t)(idx - 16) * NT32 * 512; ldoff[i] = 8192 + (idx - 16) * 512; }
        }
    }

    // swizzled fragment read offsets (shorts): row*32 + ((k/8)^(row&3))*8
    // row&3 == lane&3 here (row bases are multiples of 16) -> lane-only swizzle
    const int swz  = ((lane >> 4) ^ (lane & 3)) * 8;
    const int aoff = (wm + fr) * 32 + swz;
    const int boff = 8192 + (wn + fr) * 32 + swz;

    // prologue: tile 0 -> buf 0, tile 1 -> buf 1 (12 loads in flight)
#pragma unroll
    for (int i = 0; i < 6; ++i) gload_lds16(gp[i], lds + ldoff[i]);
#pragma unroll
    for (int i = 0; i < 6; ++i) gload_lds16(gp[i] + 512, lds + 12288 + ldoff[i]);

    for (int t = 0; t < NT32; t += 3) {
#pragma unroll
        for (int b = 0; b < 3; ++b) {
            const int kt = t + b;
            // counted wait: tile kt's 6 loads are the oldest; tile kt+1's 6 fly on
            asm volatile("s_waitcnt vmcnt(6)" ::: "memory");
            __builtin_amdgcn_s_barrier();
            __builtin_amdgcn_sched_barrier(0);
            int tt = kt + 2; if (tt >= NT32) tt -= NT32;   // tail: dummy re-stage
            const int db = (b + 2) % 3;
#pragma unroll
            for (int i = 0; i < 6; ++i)
                gload_lds16(gp[i] + (size_t)tt * 512, lds + db * 12288 + ldoff[i]);
            __builtin_amdgcn_sched_barrier(0);
            const short* pa = lds + b * 12288 + aoff;
            const short* pb = lds + b * 12288 + boff;
            bf16x8 af[8], brf[4];
#pragma unroll
            for (int m = 0; m < 8; ++m) af[m] = *(const bf16x8*)(pa + m * 512);
#pragma unroll
            for (int n = 0; n < 4; ++n) brf[n] = *(const bf16x8*)(pb + n * 512);
            __builtin_amdgcn_s_setprio(1);
#pragma unroll
            for (int m = 0; m < 8; ++m)
#pragma unroll
                for (int n = 0; n < 4; ++n)
                    acc[m][n] = __builtin_amdgcn_mfma_f32_16x16x32_bf16(
                        af[m], brf[n], acc[m][n], 0, 0, 0);
            __builtin_amdgcn_s_setprio(0);
            __builtin_amdgcn_sched_barrier(0);   // pin body: reads retire pre-barrier
        }
    }
    asm volatile("s_waitcnt vmcnt(0)" ::: "memory");

    // epilogue: + bias, fp32 store. C/D: col = lane&15, row = fq*4 + r
#pragma unroll
    for (int n = 0; n < 4; ++n) {
        const int col = n0 + wn + n * 16 + fr;
        if (col < N_DIM) {
            const float bv = bias[col];
#pragma unroll
            for (int m = 0; m < 8; ++m) {
                const int row = m0 + wm + m * 16 + fq * 4;
#pragma unroll
                for (int r = 0; r < 4; ++r)
                    out[(size_t)(row + r) * N_DIM + col] = acc[m][n][r] + bv;
            }
        }
    }
}

// ===========================================================================
// Fallback (round-1 proven path) if workspace is too small for bf16 staging
// ===========================================================================
__global__ __launch_bounds__(256, 2)
void lora_a_gemm(const float* __restrict__ x, const float* __restrict__ Abuf,
                 float* __restrict__ la) {
    __shared__ __align__(16) short sX[32 * 40];
    __shared__ __align__(16) short sA[128 * 40];
    const int tid = threadIdx.x;
    const int m0 = blockIdx.x * 32;
    const int wave = tid >> 6, lane = tid & 63;
    const int fr = lane & 15, fq = lane >> 4;
    const int wn = wave * 32;
    f32x4 acc[2][2] = {};
    const int xrow = tid >> 3, xcol = (tid & 7) * 4;
    const float* xP = x + (size_t)(m0 + xrow) * H_DIM + xcol;
    short* sXw = sX + xrow * 40 + xcol;
    const int arow = tid >> 1, ahalf = (tid & 1) * 16;
    const float* aP = Abuf + (size_t)arow * H_DIM + ahalf;
    short* sAw = sA + arow * 40 + ahalf;
    const short* sXr = sX + fr * 40 + fq * 8;
    const short* sAr = sA + (wn + fr) * 40 + fq * 8;
    for (int kt = 0; kt < H_DIM / 32; ++kt) {
        f32x4 xv = *(const f32x4*)(xP + kt * 32);
        f32x4 a0 = *(const f32x4*)(aP + kt * 32);
        f32x4 a1 = *(const f32x4*)(aP + kt * 32 + 4);
        f32x4 a2 = *(const f32x4*)(aP + kt * 32 + 8);
        f32x4 a3 = *(const f32x4*)(aP + kt * 32 + 12);
        bf16x4 xs;
        xs[0] = f2bf(xv[0]); xs[1] = f2bf(xv[1]);
        xs[2] = f2bf(xv[2]); xs[3] = f2bf(xv[3]);
        bf16x8 as0 = pack8(a0, a1), as1 = pack8(a2, a3);
        __syncthreads();
        *(bf16x4*)(sXw) = xs;
        *(bf16x8*)(sAw) = as0;
        *(bf16x8*)(sAw + 8) = as1;
        __syncthreads();
        bf16x8 xf0 = *(const bf16x8*)(sXr);
        bf16x8 xf1 = *(const bf16x8*)(sXr + 16 * 40);
        bf16x8 af0 = *(const bf16x8*)(sAr);
        bf16x8 af1 = *(const bf16x8*)(sAr + 16 * 40);
        acc[0][0] = __builtin_amdgcn_mfma_f32_16x16x32_bf16(xf0, af0, acc[0][0], 0, 0, 0);
        acc[0][1] = __builtin_amdgcn_mfma_f32_16x16x32_bf16(xf0, af1, acc[0][1], 0, 0, 0);
        acc[1][0] = __builtin_amdgcn_mfma_f32_16x16x32_bf16(xf1, af0, acc[1][0], 0, 0, 0);
        acc[1][1] = __builtin_amdgcn_mfma_f32_16x16x32_bf16(xf1, af1, acc[1][1], 0, 0, 0);
    }
#pragma unroll
    for (int ni = 0; ni < 2; ++ni) {
        const int col = wn + ni * 16 + fr;
#pragma unroll
        for (int mi = 0; mi < 2; ++mi) {
            const int row = m0 + mi * 16 + fq * 4;
#pragma unroll
            for (int r = 0; r < 4; ++r)
                la[(size_t)(row + r) * LA_WIDTH + col] = acc[mi][ni][r];
        }
    }
}

#define LDS_STRIDE 40
__global__ __launch_bounds__(256, 2)
void main_gemm(const float* __restrict__ x, const float* __restrict__ W,
               const float* __restrict__ bias, const float* __restrict__ Bbuf,
               const float* __restrict__ la, float* __restrict__ out) {
    __shared__ __align__(16) short sA[128 * LDS_STRIDE];
    __shared__ __align__(16) short sB[128 * LDS_STRIDE];
    const int tid = threadIdx.x;
    const int n0 = blockIdx.x * 128, m0 = blockIdx.y * 128;
    const int wave = tid >> 6, lane = tid & 63;
    const int wm = (wave & 1) * 64, wn = (wave >> 1) * 64;
    const int fr = lane & 15, fq = lane >> 4;
    f32x4 acc[4][4] = {};
    const int srow = tid >> 1, shalf = (tid & 1) * 16;
    const float* xP = x + (size_t)(m0 + srow) * H_DIM + shalf;
    const int wRow = n0 + srow;
    const bool wValid = wRow < N_DIM;
    const float* wP = W + (size_t)wRow * H_DIM + shalf;
    const int slice = (n0 >= D0_DIM) ? 1 : 0;
    const int oCol = wRow - slice * D0_DIM;
    const bool bValid = wValid && (oCol < (slice ? D1_DIM : D0_DIM));
    const float* laP = la + (size_t)(m0 + srow) * LA_WIDTH + slice * R_DIM + shalf;
    const float* bP = Bbuf + ((size_t)slice * D0_DIM + oCol) * R_DIM + shalf;
    short* sAw = sA + srow * LDS_STRIDE + shalf;
    short* sBw = sB + srow * LDS_STRIDE + shalf;
    const short* sAr = sA + (wm + fr) * LDS_STRIDE + fq * 8;
    const short* sBr = sB + (wn + fr) * LDS_STRIDE + fq * 8;
    const int KT = H_DIM / 32;
    for (int it = 0; it < KT + 2; ++it) {
        const float *pa, *pb;
        bool vb;
        if (it < KT) { pa = xP + it * 32; pb = wP + it * 32; vb = wValid; }
        else { const int lt = it - KT; pa = laP + lt * 32; pb = bP + lt * 32; vb = bValid; }
        f32x4 a0 = *(const f32x4*)(pa);
        f32x4 a1 = *(const f32x4*)(pa + 4);
        f32x4 a2 = *(const f32x4*)(pa + 8);
        f32x4 a3 = *(const f32x4*)(pa + 12);
        f32x4 z = {0.f, 0.f, 0.f, 0.f};
        f32x4 b0 = z, b1 = z, b2 = z, b3 = z;
        if (vb) {
            b0 = *(const f32x4*)(pb); b1 = *(const f32x4*)(pb + 4);
            b2 = *(const f32x4*)(pb + 8); b3 = *(const f32x4*)(pb + 12);
        }
        bf16x8 pa0 = pack8(a0, a1), pa1 = pack8(a2, a3);
        bf16x8 pb0 = pack8(b0, b1), pb1 = pack8(b2, b3);
        __syncthreads();
        *(bf16x8*)(sAw) = pa0; *(bf16x8*)(sAw + 8) = pa1;
        *(bf16x8*)(sBw) = pb0; *(bf16x8*)(sBw + 8) = pb1;
        __syncthreads();
        bf16x8 af[4], bfg[4];
#pragma unroll
        for (int i = 0; i < 4; ++i) af[i] = *(const bf16x8*)(sAr + i * 16 * LDS_STRIDE);
#pragma unroll
        for (int i = 0; i < 4; ++i) bfg[i] = *(const bf16x8*)(sBr + i * 16 * LDS_STRIDE);
#pragma unroll
        for (int mi = 0; mi < 4; ++mi)
#pragma unroll
            for (int ni = 0; ni < 4; ++ni)
                acc[mi][ni] = __builtin_amdgcn_mfma_f32_16x16x32_bf16(
                    af[mi], bfg[ni], acc[mi][ni], 0, 0, 0);
    }
#pragma unroll
    for (int ni = 0; ni < 4; ++ni) {
        const int col = n0 + wn + ni * 16 + fr;
        if (col < N_DIM) {
            const float bv = bias[col];
#pragma unroll
            for (int mi = 0; mi < 4; ++mi) {
                const int row = m0 + wm + mi * 16 + fq * 4;
#pragma unroll
                for (int r = 0; r < 4; ++r)
                    out[(size_t)(row + r) * N_DIM + col] = acc[mi][ni][r] + bv;
            }
        }
    }
}

extern "C" void kernel_launch(void* const* d_in, const int* in_sizes, int n_in,
                              void* d_out, int out_size, void* d_ws, size_t ws_size,
                              hipStream_t stream) {
    const float* x    = (const float*)d_in[0];
    const float* W    = (const float*)d_in[1];
    const float* bias = (const float*)d_in[2];
    const float* A    = (const float*)d_in[3];
    const float* B    = (const float*)d_in[4];
    float* out = (float*)d_out;

    const size_t xe_bytes   = (size_t)XE_RB * NT32 * 1024;            // 119,537,664
    const size_t we_bytes   = (size_t)WE_RB * NT32 * 1024;            //  31,752,192
    const size_t part_bytes = (size_t)KSPLIT * S_DIM * LA_WIDTH * 4;  //  33,554,432
    const size_t tail = (we_bytes > part_bytes) ? we_bytes : part_bytes;

    if (ws_size >= xe_bytes + tail) {
        short* xe = (short*)d_ws;
        short* we = (short*)((char*)d_ws + xe_bytes);
        float* part = (float*)((char*)d_ws + xe_bytes);  // overlaps we: consumed
                                                         // by lora_reduce before
                                                         // convert_w writes we

        lora_a_pass<<<dim3(S_DIM / 128, KSPLIT), dim3(256), 0, stream>>>(x, A, part, xe);
        lora_reduce<<<dim3(S_DIM * 16 / 256), dim3(256), 0, stream>>>(part, xe);
        convert_w<<<dim3(132 * 224 * 64 / 256), dim3(256), 0, stream>>>(W, we);
        convert_w_lora<<<dim3(WE_RB * 4 * 64 / 256), dim3(256), 0, stream>>>(B, we);
        main_gemm_tiled<<<dim3(32 * 17), dim3(256), 0, stream>>>(xe, we, bias, out);
    } else {
        float* la = (float*)d_ws;   // 4 MB scratch
        lora_a_gemm<<<dim3(S_DIM / 32), dim3(256), 0, stream>>>(x, A, la);
        main_gemm<<<dim3(N_DIM / 128 + 1, S_DIM / 128), dim3(256), 0, stream>>>(
            x, W, bias, B, la, out);
    }
}

// Round 2
// 689.106 us; speedup vs baseline: 1.2547x; 1.0521x over previous
//
#include <hip/hip_runtime.h>
#include <hip/hip_bf16.h>

// Problem constants (from reference)
#define S_DIM 8192
#define H_DIM 7168
#define D0_DIM 1536
#define D1_DIM 576
#define N_DIM 2112          // D0 + D1
#define R_DIM 64
#define LA_WIDTH 128        // 2 * R

// Extended-K fused layout: K' = H + 128 (64 lora cols per slice, complementary
// halves zeroed in Wext so one GEMM computes base + LoRA-B contribution).
#define K_EXT 7296
#define NT32 228            // K_EXT / 32 k-blocks
#define N_PAD 2176          // 17 * 128
#define KSPLIT 8
#define KCHUNK 896          // H_DIM / KSPLIT

// Tiled-swizzled staging layout for xe/we:
//   [rblock = row/16][kblock = k/32][64 slots][8 shorts]  (1 KB per block)
//   slot = (row%16)*4 + cphys,  cphys = (k%32)/8 ^ (((row%16)>>3)&1)<<1
// This is m201's measured-zero st_16x32 pattern (XOR byte-bit-5 with row-bit-3
// within each 16x32-bf16 1KB subtile): fq-group of 16 lanes -> start banks
// {0,8,16,24} x4 lanes. global_load_lds reads 1 KB contiguous into a LINEAR
// LDS dest (rule 21: swizzle baked into the staged source).
#define XE_RB 512           // S_DIM / 16
#define WE_RB 136           // N_PAD / 16

typedef __attribute__((ext_vector_type(4))) float f32x4;
typedef __attribute__((ext_vector_type(8))) short bf16x8;
typedef __attribute__((ext_vector_type(4))) short bf16x4;

__device__ __forceinline__ short f2bf(float f) {
    union { __hip_bfloat16 h; short s; } u;
    u.h = __float2bfloat16(f);
    return u.s;
}

__device__ __forceinline__ bf16x8 pack8(f32x4 a, f32x4 b) {
    bf16x8 r;
    r[0] = f2bf(a[0]); r[1] = f2bf(a[1]); r[2] = f2bf(a[2]); r[3] = f2bf(a[3]);
    r[4] = f2bf(b[0]); r[5] = f2bf(b[1]); r[6] = f2bf(b[2]); r[7] = f2bf(b[3]);
    return r;
}

__device__ __forceinline__ void gload_lds16(const short* g, short* l) {
    __builtin_amdgcn_global_load_lds(
        (const __attribute__((address_space(1))) unsigned int*)(const void*)g,
        (__attribute__((address_space(3))) unsigned int*)(void*)l, 16, 0, 0);
}

// ---------------------------------------------------------------------------
// convert_w: W fp32 [N,H] -> we tiled-swizzled bf16, kblocks 0..223
// ---------------------------------------------------------------------------
__global__ __launch_bounds__(256)
void convert_w(const float* __restrict__ W, short* __restrict__ we) {
    unsigned id = blockIdx.x * 256u + threadIdx.x;   // < 132*224*64
    unsigned rb  = id / 14336u;          // 224*64
    unsigned rem = id % 14336u;
    unsigned kb  = rem >> 6, sl = rem & 63u;
    unsigned r16 = sl >> 2;
    unsigned c   = (sl & 3u) ^ (((r16 >> 3) & 1u) << 1);
    unsigned row = rb * 16u + r16;
    unsigned k   = kb * 32u + c * 8u;
    const float* p = W + (size_t)row * H_DIM + k;
    f32x4 a = *(const f32x4*)p;
    f32x4 b = *(const f32x4*)(p + 4);
    *(bf16x8*)(we + ((size_t)rb * NT32 + kb) * 512u + sl * 8u) = pack8(a, b);
}

// convert_w_lora: fill we kblocks 224..227 (LoRA-B cols), all 136 rblocks:
//   row <  D0: [B0 row (64), zeros(64)] ; D0<=row<N: [zeros, B1 row-D0 (64)]
//   row >= N_DIM (pad): zeros
__global__ __launch_bounds__(256)
void convert_w_lora(const float* __restrict__ Bbuf, short* __restrict__ we) {
    unsigned id = blockIdx.x * 256u + threadIdx.x;   // < 136*4*64
    unsigned rb  = id >> 8;
    unsigned rem = id & 255u;
    unsigned kb4 = rem >> 6, sl = rem & 63u;
    unsigned r16 = sl >> 2;
    unsigned c   = (sl & 3u) ^ (((r16 >> 3) & 1u) << 1);
    unsigned row = rb * 16u + r16;
    unsigned k   = kb4 * 32u + c * 8u;               // 0..127 within lora cols
    bf16x8 v = {};
    if (row < N_DIM) {
        const bool s1 = row >= D0_DIM;
        const unsigned lo = s1 ? 64u : 0u;
        if (k >= lo && k < lo + 64u) {
            const float* p = Bbuf + ((size_t)(s1 ? 1u : 0u) * D0_DIM +
                                     (row - (s1 ? D0_DIM : 0u))) * R_DIM + (k - lo);
            f32x4 a = *(const f32x4*)p;
            f32x4 b = *(const f32x4*)(p + 4);
            v = pack8(a, b);
        }
    }
    *(bf16x8*)(we + ((size_t)rb * NT32 + (224u + kb4)) * 512u + sl * 8u) = v;
}

// ---------------------------------------------------------------------------
// lora_a_pass: K-split LoRA-A GEMM with convert_x fused into staging.
// Writes converted x to xe in the tiled-swizzled layout + fp32 partials.
// ---------------------------------------------------------------------------
__global__ __launch_bounds__(256, 2)
void lora_a_pass(const float* __restrict__ x, const float* __restrict__ A,
                 float* __restrict__ part, short* __restrict__ xe) {
    __shared__ __align__(16) short sX[128 * 40];
    __shared__ __align__(16) short sA[128 * 40];

    const int tid = threadIdx.x;
    const int m0 = blockIdx.x * 128;
    const int k0 = blockIdx.y * KCHUNK;
    const int wave = tid >> 6, lane = tid & 63;
    const int wm = (wave & 1) * 64, wn = (wave >> 1) * 64;
    const int fr = lane & 15, fq = lane >> 4;

    f32x4 acc[4][4] = {};

    const int srow = tid >> 1, shalf = (tid & 1) * 16;
    const float* xP = x + (size_t)(m0 + srow) * H_DIM + k0 + shalf;
    const float* aP = A + (size_t)srow * H_DIM + k0 + shalf;

    // tiled-swizzled xe destination
    const unsigned rbx = (unsigned)(m0 + srow) >> 4;
    const unsigned r16 = (unsigned)srow & 15u;
    const unsigned kb0 = (unsigned)k0 >> 5;          // blockIdx.y * 28
    const unsigned c0  = (unsigned)shalf >> 3;       // 0 or 2
    const unsigned sx  = ((r16 >> 3) & 1u) << 1;
    const unsigned sl0 = r16 * 4u + (c0 ^ sx);
    const unsigned sl1 = r16 * 4u + ((c0 + 1u) ^ sx);
    short* xeB = xe + ((size_t)rbx * NT32 + kb0) * 512u;

    short* sXw = sX + srow * 40 + shalf;
    short* sAw = sA + srow * 40 + shalf;
    const short* sXr = sX + (wm + fr) * 40 + fq * 8;
    const short* sAr = sA + (wn + fr) * 40 + fq * 8;

    for (int it = 0; it < KCHUNK / 32; ++it) {
        const float* px = xP + it * 32;
        const float* pa = aP + it * 32;
        f32x4 x0 = *(const f32x4*)(px);
        f32x4 x1 = *(const f32x4*)(px + 4);
        f32x4 x2 = *(const f32x4*)(px + 8);
        f32x4 x3 = *(const f32x4*)(px + 12);
        f32x4 a0 = *(const f32x4*)(pa);
        f32x4 a1 = *(const f32x4*)(pa + 4);
        f32x4 a2 = *(const f32x4*)(pa + 8);
        f32x4 a3 = *(const f32x4*)(pa + 12);
        bf16x8 px0 = pack8(x0, x1), px1 = pack8(x2, x3);
        bf16x8 pa0 = pack8(a0, a1), pa1 = pack8(a2, a3);

        // fused convert_x: tiled-swizzled store
        *(bf16x8*)(xeB + (size_t)it * 512 + sl0 * 8u) = px0;
        *(bf16x8*)(xeB + (size_t)it * 512 + sl1 * 8u) = px1;

        __syncthreads();
        *(bf16x8*)(sXw) = px0; *(bf16x8*)(sXw + 8) = px1;
        *(bf16x8*)(sAw) = pa0; *(bf16x8*)(sAw + 8) = pa1;
        __syncthreads();

        bf16x8 af[4], bfg[4];
#pragma unroll
        for (int i = 0; i < 4; ++i) af[i] = *(const bf16x8*)(sXr + i * 16 * 40);
#pragma unroll
        for (int i = 0; i < 4; ++i) bfg[i] = *(const bf16x8*)(sAr + i * 16 * 40);
#pragma unroll
        for (int mi = 0; mi < 4; ++mi)
#pragma unroll
            for (int ni = 0; ni < 4; ++ni)
                acc[mi][ni] = __builtin_amdgcn_mfma_f32_16x16x32_bf16(
                    af[mi], bfg[ni], acc[mi][ni], 0, 0, 0);
    }

    float* pBase = part + (size_t)blockIdx.y * S_DIM * LA_WIDTH;
#pragma unroll
    for (int ni = 0; ni < 4; ++ni) {
        const int col = wn + ni * 16 + fr;
#pragma unroll
        for (int mi = 0; mi < 4; ++mi) {
            const int row = m0 + wm + mi * 16 + fq * 4;
#pragma unroll
            for (int r = 0; r < 4; ++r)
                pBase[(size_t)(row + r) * LA_WIDTH + col] = acc[mi][ni][r];
        }
    }
}

// lora_reduce: la = sum of 8 partials -> bf16 -> xe kblocks 224..227
__global__ __launch_bounds__(256)
void lora_reduce(const float* __restrict__ part, short* __restrict__ xe) {
    unsigned id = blockIdx.x * 256u + threadIdx.x;   // < 8192*16
    unsigned row = id >> 4, c8 = (id & 15u) * 8u;
    f32x4 s0 = {}, s1 = {};
#pragma unroll
    for (int kz = 0; kz < KSPLIT; ++kz) {
        const float* p = part + ((size_t)kz * S_DIM + row) * LA_WIDTH + c8;
        s0 += *(const f32x4*)(p);
        s1 += *(const f32x4*)(p + 4);
    }
    unsigned rbx = row >> 4, r16 = row & 15u;
    unsigned kb = 224u + (c8 >> 5);
    unsigned cc = (c8 >> 3) & 3u;
    unsigned sl = r16 * 4u + (cc ^ (((r16 >> 3) & 1u) << 1));
    *(bf16x8*)(xe + ((size_t)rbx * NT32 + kb) * 512u + sl * 8u) = pack8(s0, s1);
}

// ---------------------------------------------------------------------------
// main_gemm_tiled: out = xext @ Wext^T + bias  (K = 7296 includes LoRA-B)
// BM=256 x BN=128, BK=32, ring-3 LDS (72 KB -> 2 blocks/CU), 4 waves each
// owning a 128x64 sub-tile. Counted vmcnt(6) pipeline, raw s_barrier, setprio
// around the MFMA cluster, m201-pattern swizzled ds_read.
// XCD-chunked tile mapping (T1): hardware round-robins blockIdx across the 8
// XCDs, so bx&7 = XCD. Give each XCD a contiguous chunk of 68 tiles
// (4 m-panels x 17 n-tiles, n-fast). Co-resident, k-self-synchronized blocks
// then share xe rows (17 sharers) and we rows (4 sharers) through the 4 MB
// per-XCD L2 instead of re-fetching through LLC -> fill BW ceiling rises
// from ~9 TB/s (LLC) toward L2 aggregate (~34.5 TB/s).
// ---------------------------------------------------------------------------
__global__ __launch_bounds__(256, 2)
void main_gemm_tiled(const short* __restrict__ xe, const short* __restrict__ we,
                     const float* __restrict__ bias, float* __restrict__ out) {
    __shared__ __align__(16) short lds[3 * 12288];   // 3 bufs x (A 16KB | B 8KB)

    const int tid = threadIdx.x;
    const int bx = blockIdx.x;                 // 0..543
    const int xcd = bx & 7, p = bx >> 3;
    const int tile = xcd * 68 + p;             // 544 = 8 * 68 exactly
    const int m0 = (tile / 17) * 256;
    const int n0 = (tile % 17) * 128;

    const int wave = tid >> 6, lane = tid & 63;
    const int wm = (wave & 1) * 128;
    const int wn = (wave >> 1) * 64;
    const int fr = lane & 15, fq = lane >> 4;

    f32x4 acc[8][4] = {};

    // per-tile staging: 24 x 1KB blocks (A rblocks 0..15, B rblocks 0..7);
    // wave w issues 6 contiguous-source global_load_lds.
    const short* gp[6];
    int ldoff[6];
    {
        const short* xe_pan = xe + (size_t)(m0 >> 4) * NT32 * 512 + lane * 8;
        const short* we_pan = we + (size_t)(n0 >> 4) * NT32 * 512 + lane * 8;
#pragma unroll
        for (int i = 0; i < 6; ++i) {
            const int idx = wave * 6 + i;
            if (idx < 16) { gp[i] = xe_pan + (size_t)idx * NT32 * 512; ldoff[i] = idx * 512; }
            else          { gp[i] = we_pan + (size_t)(idx - 16) * NT32 * 512; ldoff[i] = 8192 + (idx - 16) * 512; }
        }
    }

    // swizzled fragment read offsets (shorts): row*32 + (fq ^ ((row>>3)&1)<<1)*8
    const int swz  = (fq ^ ((fr >> 3) << 1)) * 8;
    const int aoff = (wm + fr) * 32 + swz;
    const int boff = 8192 + (wn + fr) * 32 + swz;

    // prologue: tile 0 -> buf 0, tile 1 -> buf 1 (12 loads in flight)
#pragma unroll
    for (int i = 0; i < 6; ++i) gload_lds16(gp[i], lds + ldoff[i]);
#pragma unroll
    for (int i = 0; i < 6; ++i) gload_lds16(gp[i] + 512, lds + 12288 + ldoff[i]);

    for (int t = 0; t < NT32; t += 3) {
#pragma unroll
        for (int b = 0; b < 3; ++b) {
            const int kt = t + b;
            // counted wait: tile kt's 6 loads are the oldest; tile kt+1's 6 fly on
            asm volatile("s_waitcnt vmcnt(6)" ::: "memory");
            __builtin_amdgcn_s_barrier();
            __builtin_amdgcn_sched_barrier(0);
            int tt = kt + 2; if (tt >= NT32) tt -= NT32;   // tail: dummy re-stage
            const int db = (b + 2) % 3;
#pragma unroll
            for (int i = 0; i < 6; ++i)
                gload_lds16(gp[i] + (size_t)tt * 512, lds + db * 12288 + ldoff[i]);
            __builtin_amdgcn_sched_barrier(0);
            const short* pa = lds + b * 12288 + aoff;
            const short* pb = lds + b * 12288 + boff;
            bf16x8 af[8], brf[4];
#pragma unroll
            for (int m = 0; m < 8; ++m) af[m] = *(const bf16x8*)(pa + m * 512);
#pragma unroll
            for (int n = 0; n < 4; ++n) brf[n] = *(const bf16x8*)(pb + n * 512);
            __builtin_amdgcn_s_setprio(1);
#pragma unroll
            for (int m = 0; m < 8; ++m)
#pragma unroll
                for (int n = 0; n < 4; ++n)
                    acc[m][n] = __builtin_amdgcn_mfma_f32_16x16x32_bf16(
                        af[m], brf[n], acc[m][n], 0, 0, 0);
            __builtin_amdgcn_s_setprio(0);
            __builtin_amdgcn_sched_barrier(0);   // pin body: reads retire pre-barrier
        }
    }
    asm volatile("s_waitcnt vmcnt(0)" ::: "memory");

    // epilogue: + bias, fp32 store. C/D: col = lane&15, row = fq*4 + r
#pragma unroll
    for (int n = 0; n < 4; ++n) {
        const int col = n0 + wn + n * 16 + fr;
        if (col < N_DIM) {
            const float bv = bias[col];
#pragma unroll
            for (int m = 0; m < 8; ++m) {
                const int row = m0 + wm + m * 16 + fq * 4;
#pragma unroll
                for (int r = 0; r < 4; ++r)
                    out[(size_t)(row + r) * N_DIM + col] = acc[m][n][r] + bv;
            }
        }
    }
}

// ===========================================================================
// Fallback (round-1 proven path) if workspace is too small for bf16 staging
// ===========================================================================
__global__ __launch_bounds__(256, 2)
void lora_a_gemm(const float* __restrict__ x, const float* __restrict__ Abuf,
                 float* __restrict__ la) {
    __shared__ __align__(16) short sX[32 * 40];
    __shared__ __align__(16) short sA[128 * 40];
    const int tid = threadIdx.x;
    const int m0 = blockIdx.x * 32;
    const int wave = tid >> 6, lane = tid & 63;
    const int fr = lane & 15, fq = lane >> 4;
    const int wn = wave * 32;
    f32x4 acc[2][2] = {};
    const int xrow = tid >> 3, xcol = (tid & 7) * 4;
    const float* xP = x + (size_t)(m0 + xrow) * H_DIM + xcol;
    short* sXw = sX + xrow * 40 + xcol;
    const int arow = tid >> 1, ahalf = (tid & 1) * 16;
    const float* aP = Abuf + (size_t)arow * H_DIM + ahalf;
    short* sAw = sA + arow * 40 + ahalf;
    const short* sXr = sX + fr * 40 + fq * 8;
    const short* sAr = sA + (wn + fr) * 40 + fq * 8;
    for (int kt = 0; kt < H_DIM / 32; ++kt) {
        f32x4 xv = *(const f32x4*)(xP + kt * 32);
        f32x4 a0 = *(const f32x4*)(aP + kt * 32);
        f32x4 a1 = *(const f32x4*)(aP + kt * 32 + 4);
        f32x4 a2 = *(const f32x4*)(aP + kt * 32 + 8);
        f32x4 a3 = *(const f32x4*)(aP + kt * 32 + 12);
        bf16x4 xs;
        xs[0] = f2bf(xv[0]); xs[1] = f2bf(xv[1]);
        xs[2] = f2bf(xv[2]); xs[3] = f2bf(xv[3]);
        bf16x8 as0 = pack8(a0, a1), as1 = pack8(a2, a3);
        __syncthreads();
        *(bf16x4*)(sXw) = xs;
        *(bf16x8*)(sAw) = as0;
        *(bf16x8*)(sAw + 8) = as1;
        __syncthreads();
        bf16x8 xf0 = *(const bf16x8*)(sXr);
        bf16x8 xf1 = *(const bf16x8*)(sXr + 16 * 40);
        bf16x8 af0 = *(const bf16x8*)(sAr);
        bf16x8 af1 = *(const bf16x8*)(sAr + 16 * 40);
        acc[0][0] = __builtin_amdgcn_mfma_f32_16x16x32_bf16(xf0, af0, acc[0][0], 0, 0, 0);
        acc[0][1] = __builtin_amdgcn_mfma_f32_16x16x32_bf16(xf0, af1, acc[0][1], 0, 0, 0);
        acc[1][0] = __builtin_amdgcn_mfma_f32_16x16x32_bf16(xf1, af0, acc[1][0], 0, 0, 0);
        acc[1][1] = __builtin_amdgcn_mfma_f32_16x16x32_bf16(xf1, af1, acc[1][1], 0, 0, 0);
    }
#pragma unroll
    for (int ni = 0; ni < 2; ++ni) {
        const int col = wn + ni * 16 + fr;
#pragma unroll
        for (int mi = 0; mi < 2; ++mi) {
            const int row = m0 + mi * 16 + fq * 4;
#pragma unroll
            for (int r = 0; r < 4; ++r)
                la[(size_t)(row + r) * LA_WIDTH + col] = acc[mi][ni][r];
        }
    }
}

#define LDS_STRIDE 40
__global__ __launch_bounds__(256, 2)
void main_gemm(const float* __restrict__ x, const float* __restrict__ W,
               const float* __restrict__ bias, const float* __restrict__ Bbuf,
               const float* __restrict__ la, float* __restrict__ out) {
    __shared__ __align__(16) short sA[128 * LDS_STRIDE];
    __shared__ __align__(16) short sB[128 * LDS_STRIDE];
    const int tid = threadIdx.x;
    const int n0 = blockIdx.x * 128, m0 = blockIdx.y * 128;
    const int wave = tid >> 6, lane = tid & 63;
    const int wm = (wave & 1) * 64, wn = (wave >> 1) * 64;
    const int fr = lane & 15, fq = lane >> 4;
    f32x4 acc[4][4] = {};
    const int srow = tid >> 1, shalf = (tid & 1) * 16;
    const float* xP = x + (size_t)(m0 + srow) * H_DIM + shalf;
    const int wRow = n0 + srow;
    const bool wValid = wRow < N_DIM;
    const float* wP = W + (size_t)wRow * H_DIM + shalf;
    const int slice = (n0 >= D0_DIM) ? 1 : 0;
    const int oCol = wRow - slice * D0_DIM;
    const bool bValid = wValid && (oCol < (slice ? D1_DIM : D0_DIM));
    const float* laP = la + (size_t)(m0 + srow) * LA_WIDTH + slice * R_DIM + shalf;
    const float* bP = Bbuf + ((size_t)slice * D0_DIM + oCol) * R_DIM + shalf;
    short* sAw = sA + srow * LDS_STRIDE + shalf;
    short* sBw = sB + srow * LDS_STRIDE + shalf;
    const short* sAr = sA + (wm + fr) * LDS_STRIDE + fq * 8;
    const short* sBr = sB + (wn + fr) * LDS_STRIDE + fq * 8;
    const int KT = H_DIM / 32;
    for (int it = 0; it < KT + 2; ++it) {
        const float *pa, *pb;
        bool vb;
        if (it < KT) { pa = xP + it * 32; pb = wP + it * 32; vb = wValid; }
        else { const int lt = it - KT; pa = laP + lt * 32; pb = bP + lt * 32; vb = bValid; }
        f32x4 a0 = *(const f32x4*)(pa);
        f32x4 a1 = *(const f32x4*)(pa + 4);
        f32x4 a2 = *(const f32x4*)(pa + 8);
        f32x4 a3 = *(const f32x4*)(pa + 12);
        f32x4 z = {0.f, 0.f, 0.f, 0.f};
        f32x4 b0 = z, b1 = z, b2 = z, b3 = z;
        if (vb) {
            b0 = *(const f32x4*)(pb); b1 = *(const f32x4*)(pb + 4);
            b2 = *(const f32x4*)(pb + 8); b3 = *(const f32x4*)(pb + 12);
        }
        bf16x8 pa0 = pack8(a0, a1), pa1 = pack8(a2, a3);
        bf16x8 pb0 = pack8(b0, b1), pb1 = pack8(b2, b3);
        __syncthreads();
        *(bf16x8*)(sAw) = pa0; *(bf16x8*)(sAw + 8) = pa1;
        *(bf16x8*)(sBw) = pb0; *(bf16x8*)(sBw + 8) = pb1;
        __syncthreads();
        bf16x8 af[4], bfg[4];
#pragma unroll
        for (int i = 0; i < 4; ++i) af[i] = *(const bf16x8*)(sAr + i * 16 * LDS_STRIDE);
#pragma unroll
        for (int i = 0; i < 4; ++i) bfg[i] = *(const bf16x8*)(sBr + i * 16 * LDS_STRIDE);
#pragma unroll
        for (int mi = 0; mi < 4; ++mi)
#pragma unroll
            for (int ni = 0; ni < 4; ++ni)
                acc[mi][ni] = __builtin_amdgcn_mfma_f32_16x16x32_bf16(
                    af[mi], bfg[ni], acc[mi][ni], 0, 0, 0);
    }
#pragma unroll
    for (int ni = 0; ni < 4; ++ni) {
        const int col = n0 + wn + ni * 16 + fr;
        if (col < N_DIM) {
            const float bv = bias[col];
#pragma unroll
            for (int mi = 0; mi < 4; ++mi) {
                const int row = m0 + wm + mi * 16 + fq * 4;
#pragma unroll
                for (int r = 0; r < 4; ++r)
                    out[(size_t)(row + r) * N_DIM + col] = acc[mi][ni][r] + bv;
            }
        }
    }
}

extern "C" void kernel_launch(void* const* d_in, const int* in_sizes, int n_in,
                              void* d_out, int out_size, void* d_ws, size_t ws_size,
                              hipStream_t stream) {
    const float* x    = (const float*)d_in[0];
    const float* W    = (const float*)d_in[1];
    const float* bias = (const float*)d_in[2];
    const float* A    = (const float*)d_in[3];
    const float* B    = (const float*)d_in[4];
    float* out = (float*)d_out;

    const size_t xe_bytes   = (size_t)XE_RB * NT32 * 1024;            // 119,537,664
    const size_t we_bytes   = (size_t)WE_RB * NT32 * 1024;            //  31,752,192
    const size_t part_bytes = (size_t)KSPLIT * S_DIM * LA_WIDTH * 4;  //  33,554,432
    const size_t tail = (we_bytes > part_bytes) ? we_bytes : part_bytes;

    if (ws_size >= xe_bytes + tail) {
        short* xe = (short*)d_ws;
        short* we = (short*)((char*)d_ws + xe_bytes);
        float* part = (float*)((char*)d_ws + xe_bytes);  // overlaps we: consumed
                                                         // by lora_reduce before
                                                         // convert_w writes we

        lora_a_pass<<<dim3(S_DIM / 128, KSPLIT), dim3(256), 0, stream>>>(x, A, part, xe);
        lora_reduce<<<dim3(S_DIM * 16 / 256), dim3(256), 0, stream>>>(part, xe);
        convert_w<<<dim3(132 * 224 * 64 / 256), dim3(256), 0, stream>>>(W, we);
        convert_w_lora<<<dim3(WE_RB * 4 * 64 / 256), dim3(256), 0, stream>>>(B, we);
        main_gemm_tiled<<<dim3(32 * 17), dim3(256), 0, stream>>>(xe, we, bias, out);
    } else {
        float* la = (float*)d_ws;   // 4 MB scratch
        lora_a_gemm<<<dim3(S_DIM / 32), dim3(256), 0, stream>>>(x, A, la);
        main_gemm<<<dim3(N_DIM / 128 + 1, S_DIM / 128), dim3(256), 0, stream>>>(
            x, W, bias, B, la, out);
    }
}

// Round 3
// 686.696 us; speedup vs baseline: 1.2591x; 1.0035x over previous
//
#include <hip/hip_runtime.h>
#include <hip/hip_bf16.h>

// Problem constants (from reference)
#define S_DIM 8192
#define H_DIM 7168
#define D0_DIM 1536
#define D1_DIM 576
#define N_DIM 2112          // D0 + D1
#define R_DIM 64
#define LA_WIDTH 128        // 2 * R

// Extended-K fused layout: K' = H + 128 (64 lora cols per slice, complementary
// halves zeroed in Wext so one GEMM computes base + LoRA-B contribution).
#define K_EXT 7296
#define NT32 228            // K_EXT / 32 k-blocks
#define N_PAD 2176          // 17 * 128
#define KSPLIT 8
#define KCHUNK 896          // H_DIM / KSPLIT

// Tiled-swizzled staging layout for xe/we (verified round 2: zero LDS bank
// conflicts in main GEMM):
//   [rblock = row/16][kblock = k/32][64 slots][8 shorts]  (1 KB per block)
//   slot = (row%16)*4 + cphys,  cphys = (k%32)/8 ^ (((row%16)>>3)&1)<<1
#define XE_RB 512           // S_DIM / 16
#define WE_RB 136           // N_PAD / 16

#define CONV_BLKS 256
#define CONV_ITEMS (WE_RB * NT32 * 64)   // 1,984,512 16B-items (all of we)

typedef __attribute__((ext_vector_type(4))) float f32x4;
typedef __attribute__((ext_vector_type(8))) short bf16x8;
typedef __attribute__((ext_vector_type(4))) short bf16x4;

__device__ __forceinline__ short f2bf(float f) {
    union { __hip_bfloat16 h; short s; } u;
    u.h = __float2bfloat16(f);
    return u.s;
}

__device__ __forceinline__ bf16x8 pack8(f32x4 a, f32x4 b) {
    bf16x8 r;
    r[0] = f2bf(a[0]); r[1] = f2bf(a[1]); r[2] = f2bf(a[2]); r[3] = f2bf(a[3]);
    r[4] = f2bf(b[0]); r[5] = f2bf(b[1]); r[6] = f2bf(b[2]); r[7] = f2bf(b[3]);
    return r;
}

__device__ __forceinline__ void gload_lds16(const short* g, short* l) {
    __builtin_amdgcn_global_load_lds(
        (const __attribute__((address_space(1))) unsigned int*)(const void*)g,
        (__attribute__((address_space(3))) unsigned int*)(void*)l, 16, 0, 0);
}

// ---------------------------------------------------------------------------
// fused_stage1: blocks [0, CONV_BLKS) grid-stride the FULL we conversion
// (W main cols, LoRA-B cols, zeroed pad rows); blocks [CONV_BLKS, +512) run
// the lora_a GEMM with fused x->bf16 conversion into xe.
//
// lora_a structure (new): LDS double-buffer + register prefetch of the next
// iteration's global loads + ONE raw s_barrier per iter with only an
// lgkmcnt(0) drain. No __syncthreads -> no vmcnt(0) drain -> the 8
// global_load_dwordx4 of iter i+1 stay in flight across iter i's compute,
// hiding HBM latency. Safety of single barrier: each wave's MFMAs consume
// ds_read results via compiler-inserted lgkm waits BEFORE that wave reaches
// the next barrier, so buffer b's reads are complete before any wave can
// pass two barriers and overwrite b.
// Output partials go via fp32 atomicAdd into la (8 adders per element).
// ---------------------------------------------------------------------------
__global__ __launch_bounds__(256, 2)
void fused_stage1(const float* __restrict__ x, const float* __restrict__ W,
                  const float* __restrict__ A, const float* __restrict__ Bbuf,
                  float* __restrict__ la, short* __restrict__ xe,
                  short* __restrict__ we) {
    if (blockIdx.x < CONV_BLKS) {
        // ---- we conversion, grid-strided ----
        const unsigned base0 = blockIdx.x * 256u + threadIdx.x;
#pragma unroll 1
        for (int itr = 0; itr < 31; ++itr) {
            unsigned id = base0 + (unsigned)itr * (CONV_BLKS * 256u);
            if (id < CONV_ITEMS) {
                unsigned rb  = id / 14592u;          // NT32*64
                unsigned rem = id % 14592u;
                unsigned kb  = rem >> 6, sl = rem & 63u;
                unsigned r16 = sl >> 2;
                unsigned c   = (sl & 3u) ^ (((r16 >> 3) & 1u) << 1);
                unsigned row = rb * 16u + r16;
                bf16x8 v = {};
                if (row < N_DIM) {
                    if (kb < 224u) {
                        unsigned k = kb * 32u + c * 8u;
                        const float* p = W + (size_t)row * H_DIM + k;
                        f32x4 a = *(const f32x4*)p;
                        f32x4 b = *(const f32x4*)(p + 4);
                        v = pack8(a, b);
                    } else {
                        unsigned kl = (kb - 224u) * 32u + c * 8u;   // 0..127
                        const bool s1 = row >= D0_DIM;
                        const unsigned lo = s1 ? 64u : 0u;
                        if (kl >= lo && kl < lo + 64u) {
                            const float* p = Bbuf + ((size_t)(s1 ? 1u : 0u) * D0_DIM +
                                                     (row - (s1 ? D0_DIM : 0u))) * R_DIM + (kl - lo);
                            f32x4 a = *(const f32x4*)p;
                            f32x4 b = *(const f32x4*)(p + 4);
                            v = pack8(a, b);
                        }
                    }
                }
                *(bf16x8*)(we + ((size_t)rb * NT32 + kb) * 512u + sl * 8u) = v;
            }
        }
        return;
    }

    // ---- lora_a + convert_x ----
    __shared__ __align__(16) short sX[2][128 * 40];
    __shared__ __align__(16) short sA[2][128 * 40];

    const int bx = blockIdx.x - CONV_BLKS;     // 0..511
    const int tid = threadIdx.x;
    const int m0 = (bx >> 3) * 128;
    const int k0 = (bx & 7) * KCHUNK;
    const int wave = tid >> 6, lane = tid & 63;
    const int wm = (wave & 1) * 64, wn = (wave >> 1) * 64;
    const int fr = lane & 15, fq = lane >> 4;

    f32x4 acc[4][4] = {};

    const int srow = tid >> 1, shalf = (tid & 1) * 16;
    const float* xP = x + (size_t)(m0 + srow) * H_DIM + k0 + shalf;
    const float* aP = A + (size_t)srow * H_DIM + k0 + shalf;

    // tiled-swizzled xe destination
    const unsigned rbx = (unsigned)(m0 + srow) >> 4;
    const unsigned r16 = (unsigned)srow & 15u;
    const unsigned kb0 = (unsigned)k0 >> 5;
    const unsigned c0  = (unsigned)shalf >> 3;       // 0 or 2
    const unsigned sx  = ((r16 >> 3) & 1u) << 1;
    const unsigned sl0 = r16 * 4u + (c0 ^ sx);
    const unsigned sl1 = r16 * 4u + ((c0 + 1u) ^ sx);
    short* xeB = xe + ((size_t)rbx * NT32 + kb0) * 512u;

    const int swoff = srow * 40 + shalf;
    const int xr_off = (wm + fr) * 40 + fq * 8;
    const int ar_off = (wn + fr) * 40 + fq * 8;

    // preload iter 0
    f32x4 cx0 = *(const f32x4*)(xP);
    f32x4 cx1 = *(const f32x4*)(xP + 4);
    f32x4 cx2 = *(const f32x4*)(xP + 8);
    f32x4 cx3 = *(const f32x4*)(xP + 12);
    f32x4 ca0 = *(const f32x4*)(aP);
    f32x4 ca1 = *(const f32x4*)(aP + 4);
    f32x4 ca2 = *(const f32x4*)(aP + 8);
    f32x4 ca3 = *(const f32x4*)(aP + 12);
    f32x4 nx0 = {}, nx1 = {}, nx2 = {}, nx3 = {};
    f32x4 na0 = {}, na1 = {}, na2 = {}, na3 = {};

#pragma unroll 1
    for (int it = 0; it < KCHUNK / 32; ++it) {
        if (it < KCHUNK / 32 - 1) {
            const float* px = xP + (it + 1) * 32;
            const float* pa = aP + (it + 1) * 32;
            nx0 = *(const f32x4*)(px);
            nx1 = *(const f32x4*)(px + 4);
            nx2 = *(const f32x4*)(px + 8);
            nx3 = *(const f32x4*)(px + 12);
            na0 = *(const f32x4*)(pa);
            na1 = *(const f32x4*)(pa + 4);
            na2 = *(const f32x4*)(pa + 8);
            na3 = *(const f32x4*)(pa + 12);
        }
        bf16x8 px0 = pack8(cx0, cx1), px1 = pack8(cx2, cx3);
        bf16x8 pa0 = pack8(ca0, ca1), pa1 = pack8(ca2, ca3);

        // fused convert_x: tiled-swizzled store to xe
        *(bf16x8*)(xeB + (size_t)it * 512 + sl0 * 8u) = px0;
        *(bf16x8*)(xeB + (size_t)it * 512 + sl1 * 8u) = px1;

        short* bX = &sX[it & 1][0];
        short* bA = &sA[it & 1][0];
        *(bf16x8*)(bX + swoff) = px0; *(bf16x8*)(bX + swoff + 8) = px1;
        *(bf16x8*)(bA + swoff) = pa0; *(bf16x8*)(bA + swoff + 8) = pa1;

        asm volatile("s_waitcnt lgkmcnt(0)" ::: "memory");
        __builtin_amdgcn_s_barrier();
        __builtin_amdgcn_sched_barrier(0);

        bf16x8 af[4], bfg[4];
#pragma unroll
        for (int i = 0; i < 4; ++i) af[i] = *(const bf16x8*)(bX + xr_off + i * 640);
#pragma unroll
        for (int i = 0; i < 4; ++i) bfg[i] = *(const bf16x8*)(bA + ar_off + i * 640);
#pragma unroll
        for (int mi = 0; mi < 4; ++mi)
#pragma unroll
            for (int ni = 0; ni < 4; ++ni)
                acc[mi][ni] = __builtin_amdgcn_mfma_f32_16x16x32_bf16(
                    af[mi], bfg[ni], acc[mi][ni], 0, 0, 0);

        cx0 = nx0; cx1 = nx1; cx2 = nx2; cx3 = nx3;
        ca0 = na0; ca1 = na1; ca2 = na2; ca3 = na3;
    }

    // partial-sum epilogue: fp32 atomics into la (8 k-split adders/elem)
#pragma unroll
    for (int ni = 0; ni < 4; ++ni) {
        const int col = wn + ni * 16 + fr;
#pragma unroll
        for (int mi = 0; mi < 4; ++mi) {
            const int row = m0 + wm + mi * 16 + fq * 4;
#pragma unroll
            for (int r = 0; r < 4; ++r)
                atomicAdd(&la[(size_t)(row + r) * LA_WIDTH + col], acc[mi][ni][r]);
        }
    }
}

// la_to_xe: la fp32 [S][128] -> bf16 -> xe kblocks 224..227 (swizzled slots)
__global__ __launch_bounds__(256)
void la_to_xe(const float* __restrict__ la, short* __restrict__ xe) {
    unsigned id = blockIdx.x * 256u + threadIdx.x;   // < 8192*16
    unsigned row = id >> 4, c8 = (id & 15u) * 8u;
    const float* p = la + (size_t)row * LA_WIDTH + c8;
    f32x4 s0 = *(const f32x4*)(p);
    f32x4 s1 = *(const f32x4*)(p + 4);
    unsigned rbx = row >> 4, r16 = row & 15u;
    unsigned kb = 224u + (c8 >> 5);
    unsigned cc = (c8 >> 3) & 3u;
    unsigned sl = r16 * 4u + (cc ^ (((r16 >> 3) & 1u) << 1));
    *(bf16x8*)(xe + ((size_t)rbx * NT32 + kb) * 512u + sl * 8u) = pack8(s0, s1);
}

// ---------------------------------------------------------------------------
// main_gemm_tiled: out = xext @ Wext^T + bias  (K = 7296 includes LoRA-B)
// UNCHANGED from round 2 (verified: 288 us, zero bank conflicts, FETCH 358MB):
// BM=256 x BN=128, BK=32, ring-3 LDS, counted vmcnt(6), raw s_barrier,
// setprio, m201 swizzle, XCD-chunked tile mapping.
// ---------------------------------------------------------------------------
__global__ __launch_bounds__(256, 2)
void main_gemm_tiled(const short* __restrict__ xe, const short* __restrict__ we,
                     const float* __restrict__ bias, float* __restrict__ out) {
    __shared__ __align__(16) short lds[3 * 12288];   // 3 bufs x (A 16KB | B 8KB)

    const int tid = threadIdx.x;
    const int bx = blockIdx.x;                 // 0..543
    const int xcd = bx & 7, p = bx >> 3;
    const int tile = xcd * 68 + p;             // 544 = 8 * 68 exactly
    const int m0 = (tile / 17) * 256;
    const int n0 = (tile % 17) * 128;

    const int wave = tid >> 6, lane = tid & 63;
    const int wm = (wave & 1) * 128;
    const int wn = (wave >> 1) * 64;
    const int fr = lane & 15, fq = lane >> 4;

    f32x4 acc[8][4] = {};

    const short* gp[6];
    int ldoff[6];
    {
        const short* xe_pan = xe + (size_t)(m0 >> 4) * NT32 * 512 + lane * 8;
        const short* we_pan = we + (size_t)(n0 >> 4) * NT32 * 512 + lane * 8;
#pragma unroll
        for (int i = 0; i < 6; ++i) {
            const int idx = wave * 6 + i;
            if (idx < 16) { gp[i] = xe_pan + (size_t)idx * NT32 * 512; ldoff[i] = idx * 512; }
            else          { gp[i] = we_pan + (size_t)(idx - 16) * NT32 * 512; ldoff[i] = 8192 + (idx - 16) * 512; }
        }
    }

    const int swz  = (fq ^ ((fr >> 3) << 1)) * 8;
    const int aoff = (wm + fr) * 32 + swz;
    const int boff = 8192 + (wn + fr) * 32 + swz;

#pragma unroll
    for (int i = 0; i < 6; ++i) gload_lds16(gp[i], lds + ldoff[i]);
#pragma unroll
    for (int i = 0; i < 6; ++i) gload_lds16(gp[i] + 512, lds + 12288 + ldoff[i]);

    for (int t = 0; t < NT32; t += 3) {
#pragma unroll
        for (int b = 0; b < 3; ++b) {
            const int kt = t + b;
            asm volatile("s_waitcnt vmcnt(6)" ::: "memory");
            __builtin_amdgcn_s_barrier();
            __builtin_amdgcn_sched_barrier(0);
            int tt = kt + 2; if (tt >= NT32) tt -= NT32;   // tail: dummy re-stage
            const int db = (b + 2) % 3;
#pragma unroll
            for (int i = 0; i < 6; ++i)
                gload_lds16(gp[i] + (size_t)tt * 512, lds + db * 12288 + ldoff[i]);
            __builtin_amdgcn_sched_barrier(0);
            const short* pa = lds + b * 12288 + aoff;
            const short* pb = lds + b * 12288 + boff;
            bf16x8 af[8], brf[4];
#pragma unroll
            for (int m = 0; m < 8; ++m) af[m] = *(const bf16x8*)(pa + m * 512);
#pragma unroll
            for (int n = 0; n < 4; ++n) brf[n] = *(const bf16x8*)(pb + n * 512);
            __builtin_amdgcn_s_setprio(1);
#pragma unroll
            for (int m = 0; m < 8; ++m)
#pragma unroll
                for (int n = 0; n < 4; ++n)
                    acc[m][n] = __builtin_amdgcn_mfma_f32_16x16x32_bf16(
                        af[m], brf[n], acc[m][n], 0, 0, 0);
            __builtin_amdgcn_s_setprio(0);
            __builtin_amdgcn_sched_barrier(0);
        }
    }
    asm volatile("s_waitcnt vmcnt(0)" ::: "memory");

#pragma unroll
    for (int n = 0; n < 4; ++n) {
        const int col = n0 + wn + n * 16 + fr;
        if (col < N_DIM) {
            const float bv = bias[col];
#pragma unroll
            for (int m = 0; m < 8; ++m) {
                const int row = m0 + wm + m * 16 + fq * 4;
#pragma unroll
                for (int r = 0; r < 4; ++r)
                    out[(size_t)(row + r) * N_DIM + col] = acc[m][n][r] + bv;
            }
        }
    }
}

// ===========================================================================
// Fallback (round-1 proven path) if workspace is too small for bf16 staging
// ===========================================================================
__global__ __launch_bounds__(256, 2)
void lora_a_gemm(const float* __restrict__ x, const float* __restrict__ Abuf,
                 float* __restrict__ la) {
    __shared__ __align__(16) short sX[32 * 40];
    __shared__ __align__(16) short sA[128 * 40];
    const int tid = threadIdx.x;
    const int m0 = blockIdx.x * 32;
    const int wave = tid >> 6, lane = tid & 63;
    const int fr = lane & 15, fq = lane >> 4;
    const int wn = wave * 32;
    f32x4 acc[2][2] = {};
    const int xrow = tid >> 3, xcol = (tid & 7) * 4;
    const float* xP = x + (size_t)(m0 + xrow) * H_DIM + xcol;
    short* sXw = sX + xrow * 40 + xcol;
    const int arow = tid >> 1, ahalf = (tid & 1) * 16;
    const float* aP = Abuf + (size_t)arow * H_DIM + ahalf;
    short* sAw = sA + arow * 40 + ahalf;
    const short* sXr = sX + fr * 40 + fq * 8;
    const short* sAr = sA + (wn + fr) * 40 + fq * 8;
    for (int kt = 0; kt < H_DIM / 32; ++kt) {
        f32x4 xv = *(const f32x4*)(xP + kt * 32);
        f32x4 a0 = *(const f32x4*)(aP + kt * 32);
        f32x4 a1 = *(const f32x4*)(aP + kt * 32 + 4);
        f32x4 a2 = *(const f32x4*)(aP + kt * 32 + 8);
        f32x4 a3 = *(const f32x4*)(aP + kt * 32 + 12);
        bf16x4 xs;
        xs[0] = f2bf(xv[0]); xs[1] = f2bf(xv[1]);
        xs[2] = f2bf(xv[2]); xs[3] = f2bf(xv[3]);
        bf16x8 as0 = pack8(a0, a1), as1 = pack8(a2, a3);
        __syncthreads();
        *(bf16x4*)(sXw) = xs;
        *(bf16x8*)(sAw) = as0;
        *(bf16x8*)(sAw + 8) = as1;
        __syncthreads();
        bf16x8 xf0 = *(const bf16x8*)(sXr);
        bf16x8 xf1 = *(const bf16x8*)(sXr + 16 * 40);
        bf16x8 af0 = *(const bf16x8*)(sAr);
        bf16x8 af1 = *(const bf16x8*)(sAr + 16 * 40);
        acc[0][0] = __builtin_amdgcn_mfma_f32_16x16x32_bf16(xf0, af0, acc[0][0], 0, 0, 0);
        acc[0][1] = __builtin_amdgcn_mfma_f32_16x16x32_bf16(xf0, af1, acc[0][1], 0, 0, 0);
        acc[1][0] = __builtin_amdgcn_mfma_f32_16x16x32_bf16(xf1, af0, acc[1][0], 0, 0, 0);
        acc[1][1] = __builtin_amdgcn_mfma_f32_16x16x32_bf16(xf1, af1, acc[1][1], 0, 0, 0);
    }
#pragma unroll
    for (int ni = 0; ni < 2; ++ni) {
        const int col = wn + ni * 16 + fr;
#pragma unroll
        for (int mi = 0; mi < 2; ++mi) {
            const int row = m0 + mi * 16 + fq * 4;
#pragma unroll
            for (int r = 0; r < 4; ++r)
                la[(size_t)(row + r) * LA_WIDTH + col] = acc[mi][ni][r];
        }
    }
}

#define LDS_STRIDE 40
__global__ __launch_bounds__(256, 2)
void main_gemm(const float* __restrict__ x, const float* __restrict__ W,
               const float* __restrict__ bias, const float* __restrict__ Bbuf,
               const float* __restrict__ la, float* __restrict__ out) {
    __shared__ __align__(16) short sA[128 * LDS_STRIDE];
    __shared__ __align__(16) short sB[128 * LDS_STRIDE];
    const int tid = threadIdx.x;
    const int n0 = blockIdx.x * 128, m0 = blockIdx.y * 128;
    const int wave = tid >> 6, lane = tid & 63;
    const int wm = (wave & 1) * 64, wn = (wave >> 1) * 64;
    const int fr = lane & 15, fq = lane >> 4;
    f32x4 acc[4][4] = {};
    const int srow = tid >> 1, shalf = (tid & 1) * 16;
    const float* xP = x + (size_t)(m0 + srow) * H_DIM + shalf;
    const int wRow = n0 + srow;
    const bool wValid = wRow < N_DIM;
    const float* wP = W + (size_t)wRow * H_DIM + shalf;
    const int slice = (n0 >= D0_DIM) ? 1 : 0;
    const int oCol = wRow - slice * D0_DIM;
    const bool bValid = wValid && (oCol < (slice ? D1_DIM : D0_DIM));
    const float* laP = la + (size_t)(m0 + srow) * LA_WIDTH + slice * R_DIM + shalf;
    const float* bP = Bbuf + ((size_t)slice * D0_DIM + oCol) * R_DIM + shalf;
    short* sAw = sA + srow * LDS_STRIDE + shalf;
    short* sBw = sB + srow * LDS_STRIDE + shalf;
    const short* sAr = sA + (wm + fr) * LDS_STRIDE + fq * 8;
    const short* sBr = sB + (wn + fr) * LDS_STRIDE + fq * 8;
    const int KT = H_DIM / 32;
    for (int it = 0; it < KT + 2; ++it) {
        const float *pa, *pb;
        bool vb;
        if (it < KT) { pa = xP + it * 32; pb = wP + it * 32; vb = wValid; }
        else { const int lt = it - KT; pa = laP + lt * 32; pb = bP + lt * 32; vb = bValid; }
        f32x4 a0 = *(const f32x4*)(pa);
        f32x4 a1 = *(const f32x4*)(pa + 4);
        f32x4 a2 = *(const f32x4*)(pa + 8);
        f32x4 a3 = *(const f32x4*)(pa + 12);
        f32x4 z = {0.f, 0.f, 0.f, 0.f};
        f32x4 b0 = z, b1 = z, b2 = z, b3 = z;
        if (vb) {
            b0 = *(const f32x4*)(pb); b1 = *(const f32x4*)(pb + 4);
            b2 = *(const f32x4*)(pb + 8); b3 = *(const f32x4*)(pb + 12);
        }
        bf16x8 pa0 = pack8(a0, a1), pa1 = pack8(a2, a3);
        bf16x8 pb0 = pack8(b0, b1), pb1 = pack8(b2, b3);
        __syncthreads();
        *(bf16x8*)(sAw) = pa0; *(bf16x8*)(sAw + 8) = pa1;
        *(bf16x8*)(sBw) = pb0; *(bf16x8*)(sBw + 8) = pb1;
        __syncthreads();
        bf16x8 af[4], bfg[4];
#pragma unroll
        for (int i = 0; i < 4; ++i) af[i] = *(const bf16x8*)(sAr + i * 16 * LDS_STRIDE);
#pragma unroll
        for (int i = 0; i < 4; ++i) bfg[i] = *(const bf16x8*)(sBr + i * 16 * LDS_STRIDE);
#pragma unroll
        for (int mi = 0; mi < 4; ++mi)
#pragma unroll
            for (int ni = 0; ni < 4; ++ni)
                acc[mi][ni] = __builtin_amdgcn_mfma_f32_16x16x32_bf16(
                    af[mi], bfg[ni], acc[mi][ni], 0, 0, 0);
    }
#pragma unroll
    for (int ni = 0; ni < 4; ++ni) {
        const int col = n0 + wn + ni * 16 + fr;
        if (col < N_DIM) {
            const float bv = bias[col];
#pragma unroll
            for (int mi = 0; mi < 4; ++mi) {
                const int row = m0 + wm + mi * 16 + fq * 4;
#pragma unroll
                for (int r = 0; r < 4; ++r)
                    out[(size_t)(row + r) * N_DIM + col] = acc[mi][ni][r] + bv;
            }
        }
    }
}

extern "C" void kernel_launch(void* const* d_in, const int* in_sizes, int n_in,
                              void* d_out, int out_size, void* d_ws, size_t ws_size,
                              hipStream_t stream) {
    const float* x    = (const float*)d_in[0];
    const float* W    = (const float*)d_in[1];
    const float* bias = (const float*)d_in[2];
    const float* A    = (const float*)d_in[3];
    const float* B    = (const float*)d_in[4];
    float* out = (float*)d_out;

    const size_t xe_bytes = (size_t)XE_RB * NT32 * 1024;   // 119,537,664
    const size_t we_bytes = (size_t)WE_RB * NT32 * 1024;   //  31,752,192
    const size_t la_bytes = (size_t)S_DIM * LA_WIDTH * 4;  //   4,194,304

    if (ws_size >= xe_bytes + we_bytes) {
        short* xe = (short*)d_ws;
        short* we = (short*)((char*)d_ws + xe_bytes);
        // la scratch lives in the HEAD of the output buffer: zeroed here,
        // accumulated by fused_stage1, consumed by la_to_xe, then fully
        // overwritten by main_gemm_tiled's epilogue.
        float* la = (float*)d_out;

        hipMemsetAsync(d_out, 0, la_bytes, stream);
        fused_stage1<<<dim3(CONV_BLKS + 512), dim3(256), 0, stream>>>(
            x, W, A, B, la, xe, we);
        la_to_xe<<<dim3(S_DIM * 16 / 256), dim3(256), 0, stream>>>(la, xe);
        main_gemm_tiled<<<dim3(32 * 17), dim3(256), 0, stream>>>(xe, we, bias, out);
    } else {
        float* la = (float*)d_ws;   // 4 MB scratch
        lora_a_gemm<<<dim3(S_DIM / 32), dim3(256), 0, stream>>>(x, A, la);
        main_gemm<<<dim3(N_DIM / 128 + 1, S_DIM / 128), dim3(256), 0, stream>>>(
            x, W, bias, B, la, out);
    }
}